// Round 6
// baseline (571.018 us; speedup 1.0000x reference)
//
#include <hip/hip_runtime.h>
#include <hip/hip_bf16.h>

// GraphSage: 3x SAGEConv(mean) + linear head.
// Precision: packed split-bf16 (uint32 = hi<<16|lo, val = f(hi)+f(lo)).
// GEMM: weight-stationary MFMA, 1 tile/block. Head fused into layer 2.
// Aggregate: 2 nodes/wave, 32-lane x uint4 row gathers, 8-deep unroll
// (16 outstanding 512B gathers/wave — MLP-bound fix for the 55us agg).
// CSR build once per call (edge_index int32: [src[0..E), dst[0..E)]).

constexpr int NN = 50000;
constexpr int NE = 800000;
constexpr int NCH = (NN + 255) / 256;
constexpr int NTILE = NN / 16;          // 3125 exact

using bf16x8 = __attribute__((ext_vector_type(8))) short;
using f32x4  = __attribute__((ext_vector_type(4))) float;

__device__ __forceinline__ unsigned short bf16_rne(float f) {
    unsigned u = __float_as_uint(f);
    unsigned r = (u + 0x7FFFu + ((u >> 16) & 1u)) >> 16;
    return (unsigned short)r;
}
__device__ __forceinline__ float bf16_f(unsigned short h) {
    return __uint_as_float(((unsigned)h) << 16);
}
__device__ __forceinline__ unsigned pack_split(float v) {
    unsigned short hi = bf16_rne(v);
    float r = v - bf16_f(hi);
    unsigned short lo = bf16_rne(r);
    return (((unsigned)hi) << 16) | (unsigned)lo;
}
__device__ __forceinline__ float unpack_f(unsigned p) {
    // f(hi) + f(lo): and/shl + 2 adds
    return __uint_as_float(p & 0xFFFF0000u) + __uint_as_float(p << 16);
}

// ---------------- CSR build ----------------

__global__ void k_zero_int(int* __restrict__ a, int n) {
    int i = blockIdx.x * blockDim.x + threadIdx.x;
    if (i < n) a[i] = 0;
}

__global__ void k_count(const int* __restrict__ ei, int* __restrict__ cnt) {
    int e = blockIdx.x * blockDim.x + threadIdx.x;
    if (e < NE) atomicAdd(&cnt[ei[NE + e]], 1);
}

__global__ void k_chunk_sums(const int* __restrict__ cnt, int* __restrict__ partial) {
    __shared__ int ws[4];
    int i = blockIdx.x * 256 + threadIdx.x;
    int v = (i < NN) ? cnt[i] : 0;
    for (int o = 32; o > 0; o >>= 1) v += __shfl_down(v, o);
    int lane = threadIdx.x & 63, wave = threadIdx.x >> 6;
    if (lane == 0) ws[wave] = v;
    __syncthreads();
    if (threadIdx.x == 0) partial[blockIdx.x] = ws[0] + ws[1] + ws[2] + ws[3];
}

__global__ void k_scan_partials(int* __restrict__ partial, int n) {
    __shared__ int ws[4];
    int t = threadIdx.x;
    int orig = (t < n) ? partial[t] : 0;
    int v = orig;
    int lane = t & 63, wave = t >> 6;
    for (int o = 1; o < 64; o <<= 1) { int u = __shfl_up(v, o); if (lane >= o) v += u; }
    if (lane == 63) ws[wave] = v;
    __syncthreads();
    int off = 0;
    for (int w = 0; w < 4; ++w) if (w < wave) off += ws[w];
    if (t < n) partial[t] = v + off - orig;
}

__global__ void k_scan_chunks(const int* __restrict__ cnt, const int* __restrict__ partial,
                              int* __restrict__ cursor) {
    __shared__ int ws[4];
    int i = blockIdx.x * 256 + threadIdx.x;
    int orig = (i < NN) ? cnt[i] : 0;
    int v = orig;
    int lane = threadIdx.x & 63, wave = threadIdx.x >> 6;
    for (int o = 1; o < 64; o <<= 1) { int u = __shfl_up(v, o); if (lane >= o) v += u; }
    if (lane == 63) ws[wave] = v;
    __syncthreads();
    int off = partial[blockIdx.x];
    for (int w = 0; w < 4; ++w) if (w < wave) off += ws[w];
    if (i < NN) cursor[i] = v - orig + off;
}

__global__ void k_scatter(const int* __restrict__ ei, int* __restrict__ cursor,
                          int* __restrict__ perm) {
    int e = blockIdx.x * blockDim.x + threadIdx.x;
    if (e < NE) {
        int s = ei[e];
        int d = ei[NE + e];
        int pos = atomicAdd(&cursor[d], 1);
        perm[pos] = s;
    }
}

// ---------------- packing ----------------

__global__ void k_pack_x(const float* __restrict__ x, unsigned* __restrict__ xp) {
    int i = blockIdx.x * blockDim.x + threadIdx.x;
    constexpr int TOT = NN * 128 / 4;
    if (i < TOT) {
        float4 v = ((const float4*)x)[i];
        uint4 o;
        o.x = pack_split(v.x); o.y = pack_split(v.y);
        o.z = pack_split(v.z); o.w = pack_split(v.w);
        ((uint4*)xp)[i] = o;
    }
}

// Wl,Wr [128 out][128 in] fp32 -> combined hi/lo bf16 planes [128 c][256 k]
__global__ void k_pack_w(const float* __restrict__ Wl, const float* __restrict__ Wr,
                         unsigned short* __restrict__ whi, unsigned short* __restrict__ wlo) {
    int i = blockIdx.x * blockDim.x + threadIdx.x;
    if (i < 128 * 256) {
        int c = i >> 8;
        int k = i & 255;
        float v = (k < 128) ? Wl[c * 128 + k] : Wr[c * 128 + (k - 128)];
        unsigned short hi = bf16_rne(v);
        whi[i] = hi;
        wlo[i] = bf16_rne(v - bf16_f(hi));
    }
}

__global__ void k_init_out(float* __restrict__ out, const float* __restrict__ bf) {
    int i = blockIdx.x * blockDim.x + threadIdx.x;
    if (i < NN) out[i] = bf[0];
}

// ---------------- aggregate (mean over CSR neighbors) ----------------
// 2 nodes per wave: 32-lane half covers a full 512B row as uint4 (16B/lane).
// 8-deep unroll -> 16 outstanding row-gathers per wave.
__global__ __launch_bounds__(256) void k_aggregate(const unsigned* __restrict__ hp,
        const int* __restrict__ cursor, const int* __restrict__ cnt,
        const int* __restrict__ perm, unsigned* __restrict__ outp) {
    int wave = __builtin_amdgcn_readfirstlane(threadIdx.x >> 6);
    int lane = threadIdx.x & 63;
    int sub = lane >> 5;          // which of the 2 nodes
    int sl = lane & 31;           // uint4 index within row (32*16B = 512B)
    int node = blockIdx.x * 8 + wave * 2 + sub;
    if (node >= NN) return;
    int deg = cnt[node];
    int start = cursor[node] - deg;
    const uint4* base = (const uint4*)hp;   // row stride = 32 uint4
    float a0 = 0.f, a1 = 0.f, a2 = 0.f, a3 = 0.f;
    int j = 0;
    for (; j + 8 <= deg; j += 8) {
        int s[8];
#pragma unroll
        for (int u = 0; u < 8; ++u) s[u] = perm[start + j + u];
        uint4 q[8];
#pragma unroll
        for (int u = 0; u < 8; ++u) q[u] = base[(size_t)s[u] * 32 + sl];
#pragma unroll
        for (int u = 0; u < 8; ++u) {
            a0 += unpack_f(q[u].x); a1 += unpack_f(q[u].y);
            a2 += unpack_f(q[u].z); a3 += unpack_f(q[u].w);
        }
    }
    for (; j + 2 <= deg; j += 2) {
        int s0 = perm[start + j];
        int s1 = perm[start + j + 1];
        uint4 q0 = base[(size_t)s0 * 32 + sl];
        uint4 q1 = base[(size_t)s1 * 32 + sl];
        a0 += unpack_f(q0.x) + unpack_f(q1.x);
        a1 += unpack_f(q0.y) + unpack_f(q1.y);
        a2 += unpack_f(q0.z) + unpack_f(q1.z);
        a3 += unpack_f(q0.w) + unpack_f(q1.w);
    }
    if (j < deg) {
        int s = perm[start + j];
        uint4 q = base[(size_t)s * 32 + sl];
        a0 += unpack_f(q.x); a1 += unpack_f(q.y);
        a2 += unpack_f(q.z); a3 += unpack_f(q.w);
    }
    float inv = 1.0f / (float)(deg > 1 ? deg : 1);
    uint4 o;
    o.x = pack_split(a0 * inv);
    o.y = pack_split(a1 * inv);
    o.z = pack_split(a2 * inv);
    o.w = pack_split(a3 * inv);
    ((uint4*)(outp + (size_t)node * 128))[sl] = o;
}

// ---------------- weight-stationary MFMA GEMM (1 tile/block) ----------------
// out[n][c] = relu( bias[c] + sum_k [A0|A1][n][k] W[c][k] )
// Wave w owns cols [32w,32w+32): B hi/lo frags hoisted to 128 VGPRs.
// In-place safe: block reads only its own 16 rows; __syncthreads() before writes.
__global__ __launch_bounds__(256, 2) void k_gemm_ws(
        const unsigned* __restrict__ A0p, const unsigned* __restrict__ A1p,
        const unsigned short* __restrict__ Whi, const unsigned short* __restrict__ Wlo,
        const float* __restrict__ bias, unsigned* __restrict__ outp) {
    int wave = __builtin_amdgcn_readfirstlane(threadIdx.x >> 6);
    int lane = threadIdx.x & 63;
    int row = lane & 15;        // A row in tile / D col in ct-tile
    int kb = lane >> 4;         // k-subblock 0..3
    int ct0 = wave * 2;

    bf16x8 bh[2][8], bl[2][8];
#pragma unroll
    for (int c = 0; c < 2; ++c)
#pragma unroll
        for (int kc = 0; kc < 8; ++kc) {
            size_t widx = (size_t)((ct0 + c) * 16 + row) * 256 + kc * 32 + kb * 8;
            bh[c][kc] = *(const bf16x8*)(Whi + widx);
            bl[c][kc] = *(const bf16x8*)(Wlo + widx);
        }
    float b0 = bias[ct0 * 16 + row];
    float b1 = bias[ct0 * 16 + 16 + row];

    int n0 = blockIdx.x * 16;
    const unsigned* a0 = A0p + (size_t)(n0 + row) * 128 + kb * 8;
    const unsigned* a1 = A1p + (size_t)(n0 + row) * 128 + kb * 8;
    f32x4 acc0 = {0.f, 0.f, 0.f, 0.f};
    f32x4 acc1 = {0.f, 0.f, 0.f, 0.f};
#pragma unroll
    for (int kc = 0; kc < 8; ++kc) {
        const unsigned* ap = ((kc < 4) ? a0 : a1) + (kc & 3) * 32;
        uint4 q0 = *(const uint4*)ap;
        uint4 q1 = *(const uint4*)(ap + 4);
        unsigned pk[8] = {q0.x, q0.y, q0.z, q0.w, q1.x, q1.y, q1.z, q1.w};
        bf16x8 ah, al;
#pragma unroll
        for (int j = 0; j < 8; ++j) {
            ah[j] = (short)(pk[j] >> 16);
            al[j] = (short)(pk[j] & 0xFFFFu);
        }
        acc0 = __builtin_amdgcn_mfma_f32_16x16x32_bf16(ah, bh[0][kc], acc0, 0, 0, 0);
        acc0 = __builtin_amdgcn_mfma_f32_16x16x32_bf16(al, bh[0][kc], acc0, 0, 0, 0);
        acc0 = __builtin_amdgcn_mfma_f32_16x16x32_bf16(ah, bl[0][kc], acc0, 0, 0, 0);
        acc1 = __builtin_amdgcn_mfma_f32_16x16x32_bf16(ah, bh[1][kc], acc1, 0, 0, 0);
        acc1 = __builtin_amdgcn_mfma_f32_16x16x32_bf16(al, bh[1][kc], acc1, 0, 0, 0);
        acc1 = __builtin_amdgcn_mfma_f32_16x16x32_bf16(ah, bl[1][kc], acc1, 0, 0, 0);
    }
    __syncthreads();   // all waves' reads of this tile's rows precede writes
    int cb0 = ct0 * 16 + row;
#pragma unroll
    for (int r = 0; r < 4; ++r) {
        int n = n0 + kb * 4 + r;         // D: col=lane&15, row=(lane>>4)*4+reg
        unsigned* orow = outp + (size_t)n * 128;
        orow[cb0]      = pack_split(fmaxf(acc0[r] + b0, 0.f));
        orow[cb0 + 16] = pack_split(fmaxf(acc1[r] + b1, 0.f));
    }
}

// layer-2 variant: head fused — out[n] += sum_c relu(h3[n][c]) * Wf[c]
__global__ __launch_bounds__(256, 2) void k_gemm_head(
        const unsigned* __restrict__ A0p, const unsigned* __restrict__ A1p,
        const unsigned short* __restrict__ Whi, const unsigned short* __restrict__ Wlo,
        const float* __restrict__ bias, const float* __restrict__ Wf,
        float* __restrict__ out) {
    int wave = __builtin_amdgcn_readfirstlane(threadIdx.x >> 6);
    int lane = threadIdx.x & 63;
    int row = lane & 15;
    int kb = lane >> 4;
    int ct0 = wave * 2;

    bf16x8 bh[2][8], bl[2][8];
#pragma unroll
    for (int c = 0; c < 2; ++c)
#pragma unroll
        for (int kc = 0; kc < 8; ++kc) {
            size_t widx = (size_t)((ct0 + c) * 16 + row) * 256 + kc * 32 + kb * 8;
            bh[c][kc] = *(const bf16x8*)(Whi + widx);
            bl[c][kc] = *(const bf16x8*)(Wlo + widx);
        }
    float b0 = bias[ct0 * 16 + row];
    float b1 = bias[ct0 * 16 + 16 + row];
    float w0 = Wf[ct0 * 16 + row];
    float w1 = Wf[ct0 * 16 + 16 + row];

    int n0 = blockIdx.x * 16;
    const unsigned* a0 = A0p + (size_t)(n0 + row) * 128 + kb * 8;
    const unsigned* a1 = A1p + (size_t)(n0 + row) * 128 + kb * 8;
    f32x4 acc0 = {0.f, 0.f, 0.f, 0.f};
    f32x4 acc1 = {0.f, 0.f, 0.f, 0.f};
#pragma unroll
    for (int kc = 0; kc < 8; ++kc) {
        const unsigned* ap = ((kc < 4) ? a0 : a1) + (kc & 3) * 32;
        uint4 q0 = *(const uint4*)ap;
        uint4 q1 = *(const uint4*)(ap + 4);
        unsigned pk[8] = {q0.x, q0.y, q0.z, q0.w, q1.x, q1.y, q1.z, q1.w};
        bf16x8 ah, al;
#pragma unroll
        for (int j = 0; j < 8; ++j) {
            ah[j] = (short)(pk[j] >> 16);
            al[j] = (short)(pk[j] & 0xFFFFu);
        }
        acc0 = __builtin_amdgcn_mfma_f32_16x16x32_bf16(ah, bh[0][kc], acc0, 0, 0, 0);
        acc0 = __builtin_amdgcn_mfma_f32_16x16x32_bf16(al, bh[0][kc], acc0, 0, 0, 0);
        acc0 = __builtin_amdgcn_mfma_f32_16x16x32_bf16(ah, bl[0][kc], acc0, 0, 0, 0);
        acc1 = __builtin_amdgcn_mfma_f32_16x16x32_bf16(ah, bh[1][kc], acc1, 0, 0, 0);
        acc1 = __builtin_amdgcn_mfma_f32_16x16x32_bf16(al, bh[1][kc], acc1, 0, 0, 0);
        acc1 = __builtin_amdgcn_mfma_f32_16x16x32_bf16(ah, bl[1][kc], acc1, 0, 0, 0);
    }
    float part[4];
#pragma unroll
    for (int r = 0; r < 4; ++r)
        part[r] = fmaxf(acc0[r] + b0, 0.f) * w0 + fmaxf(acc1[r] + b1, 0.f) * w1;
#pragma unroll
    for (int o = 1; o < 16; o <<= 1) {
#pragma unroll
        for (int r = 0; r < 4; ++r) part[r] += __shfl_xor(part[r], o);
    }
    if (row == 0) {
#pragma unroll
        for (int r = 0; r < 4; ++r) atomicAdd(&out[n0 + kb * 4 + r], part[r]);
    }
}

extern "C" void kernel_launch(void* const* d_in, const int* in_sizes, int n_in,
                              void* d_out, int out_size, void* d_ws, size_t ws_size,
                              hipStream_t stream) {
    const float* x   = (const float*)d_in[0];
    const int*   ei  = (const int*)d_in[1];
    const float* Wl0 = (const float*)d_in[2];
    const float* bl0 = (const float*)d_in[3];
    const float* Wr0 = (const float*)d_in[4];
    const float* Wl1 = (const float*)d_in[5];
    const float* bl1 = (const float*)d_in[6];
    const float* Wr1 = (const float*)d_in[7];
    const float* Wl2 = (const float*)d_in[8];
    const float* bl2 = (const float*)d_in[9];
    const float* Wr2 = (const float*)d_in[10];
    const float* Wf  = (const float*)d_in[11];
    const float* bf  = (const float*)d_in[12];
    float* out = (float*)d_out;

    char* p = (char*)d_ws;
    auto alloc = [&](size_t n) { void* r = (void*)p; p += (n + 255) & ~(size_t)255; return r; };
    int*            cnt     = (int*)alloc((size_t)NN * 4);
    int*            cursor  = (int*)alloc((size_t)NN * 4);
    int*            partial = (int*)alloc(256 * 4);
    int*            perm    = (int*)alloc((size_t)NE * 4);
    unsigned*       sbuf    = (unsigned*)alloc((size_t)NN * 128 * 4);
    unsigned*       hp      = (unsigned*)alloc((size_t)NN * 128 * 4);
    unsigned short* whi     = (unsigned short*)alloc((size_t)3 * 128 * 256 * 2);
    unsigned short* wlo     = (unsigned short*)alloc((size_t)3 * 128 * 256 * 2);

    dim3 b256(256);
    // CSR build
    k_zero_int<<<dim3((NN + 255) / 256), b256, 0, stream>>>(cnt, NN);
    k_count<<<dim3((NE + 255) / 256), b256, 0, stream>>>(ei, cnt);
    k_chunk_sums<<<dim3(NCH), b256, 0, stream>>>(cnt, partial);
    k_scan_partials<<<dim3(1), b256, 0, stream>>>(partial, NCH);
    k_scan_chunks<<<dim3(NCH), b256, 0, stream>>>(cnt, partial, cursor);
    k_scatter<<<dim3((NE + 255) / 256), b256, 0, stream>>>(ei, cursor, perm);

    // packing + out init
    k_pack_x<<<dim3((NN * 128 / 4 + 255) / 256), b256, 0, stream>>>(x, hp);
    k_pack_w<<<dim3(128), b256, 0, stream>>>(Wl0, Wr0, whi + 0 * 32768, wlo + 0 * 32768);
    k_pack_w<<<dim3(128), b256, 0, stream>>>(Wl1, Wr1, whi + 1 * 32768, wlo + 1 * 32768);
    k_pack_w<<<dim3(128), b256, 0, stream>>>(Wl2, Wr2, whi + 2 * 32768, wlo + 2 * 32768);
    k_init_out<<<dim3((NN + 255) / 256), b256, 0, stream>>>(out, bf);

    dim3 gAgg((NN + 7) / 8);    // 2 nodes per wave, 8 per block
    dim3 gGemm(NTILE);          // 1 tile (16 nodes) per block

    // layer 0
    k_aggregate<<<gAgg, b256, 0, stream>>>(hp, cursor, cnt, perm, sbuf);
    k_gemm_ws<<<gGemm, b256, 0, stream>>>(sbuf, hp, whi + 0 * 32768, wlo + 0 * 32768, bl0, hp);
    // layer 1 (in place)
    k_aggregate<<<gAgg, b256, 0, stream>>>(hp, cursor, cnt, perm, sbuf);
    k_gemm_ws<<<gGemm, b256, 0, stream>>>(sbuf, hp, whi + 1 * 32768, wlo + 1 * 32768, bl1, hp);
    // layer 2 + fused head
    k_aggregate<<<gAgg, b256, 0, stream>>>(hp, cursor, cnt, perm, sbuf);
    k_gemm_head<<<gGemm, b256, 0, stream>>>(sbuf, hp, whi + 2 * 32768, wlo + 2 * 32768, bl2, Wf, out);
}

// Round 7
// 455.940 us; speedup vs baseline: 1.2524x; 1.2524x over previous
//
#include <hip/hip_runtime.h>
#include <hip/hip_bf16.h>

// GraphSage: 3x SAGEConv(mean) + linear head.
// Precision: packed split-bf16 (uint32 = hi<<16|lo, val = f(hi)+f(lo)).
// GEMM: weight-stationary MFMA with GRID-STRIDE tile loop (512 blocks).
//   NOTE: the grid-stride loop is load-bearing — it forces the compiler to
//   keep the 128-VGPR B-fragment set live across tiles (round 6 regression:
//   1 tile/block -> VGPR=32, B re-read 3125x, 75us vs <55us).
// Aggregate: 1 node/wave, uint2 lanes, 16-deep gather unroll (8KB in flight).
// Head fused into layer-2 GEMM. CSR built once per call (edge_index int32).

constexpr int NN = 50000;
constexpr int NE = 800000;
constexpr int NCH = (NN + 255) / 256;
constexpr int NTILE = NN / 16;          // 3125 exact

using bf16x8 = __attribute__((ext_vector_type(8))) short;
using f32x4  = __attribute__((ext_vector_type(4))) float;

__device__ __forceinline__ unsigned short bf16_rne(float f) {
    unsigned u = __float_as_uint(f);
    unsigned r = (u + 0x7FFFu + ((u >> 16) & 1u)) >> 16;
    return (unsigned short)r;
}
__device__ __forceinline__ float bf16_f(unsigned short h) {
    return __uint_as_float(((unsigned)h) << 16);
}
__device__ __forceinline__ unsigned pack_split(float v) {
    unsigned short hi = bf16_rne(v);
    float r = v - bf16_f(hi);
    unsigned short lo = bf16_rne(r);
    return (((unsigned)hi) << 16) | (unsigned)lo;
}
__device__ __forceinline__ float unpack_f(unsigned p) {
    return __uint_as_float(p & 0xFFFF0000u) + __uint_as_float(p << 16);
}

// ---------------- CSR build ----------------

__global__ void k_zero_int(int* __restrict__ a, int n) {
    int i = blockIdx.x * blockDim.x + threadIdx.x;
    if (i < n) a[i] = 0;
}

__global__ void k_count(const int* __restrict__ ei, int* __restrict__ cnt) {
    int e = blockIdx.x * blockDim.x + threadIdx.x;
    if (e < NE) atomicAdd(&cnt[ei[NE + e]], 1);
}

__global__ void k_chunk_sums(const int* __restrict__ cnt, int* __restrict__ partial) {
    __shared__ int ws[4];
    int i = blockIdx.x * 256 + threadIdx.x;
    int v = (i < NN) ? cnt[i] : 0;
    for (int o = 32; o > 0; o >>= 1) v += __shfl_down(v, o);
    int lane = threadIdx.x & 63, wave = threadIdx.x >> 6;
    if (lane == 0) ws[wave] = v;
    __syncthreads();
    if (threadIdx.x == 0) partial[blockIdx.x] = ws[0] + ws[1] + ws[2] + ws[3];
}

__global__ void k_scan_partials(int* __restrict__ partial, int n) {
    __shared__ int ws[4];
    int t = threadIdx.x;
    int orig = (t < n) ? partial[t] : 0;
    int v = orig;
    int lane = t & 63, wave = t >> 6;
    for (int o = 1; o < 64; o <<= 1) { int u = __shfl_up(v, o); if (lane >= o) v += u; }
    if (lane == 63) ws[wave] = v;
    __syncthreads();
    int off = 0;
    for (int w = 0; w < 4; ++w) if (w < wave) off += ws[w];
    if (t < n) partial[t] = v + off - orig;
}

__global__ void k_scan_chunks(const int* __restrict__ cnt, const int* __restrict__ partial,
                              int* __restrict__ cursor) {
    __shared__ int ws[4];
    int i = blockIdx.x * 256 + threadIdx.x;
    int orig = (i < NN) ? cnt[i] : 0;
    int v = orig;
    int lane = threadIdx.x & 63, wave = threadIdx.x >> 6;
    for (int o = 1; o < 64; o <<= 1) { int u = __shfl_up(v, o); if (lane >= o) v += u; }
    if (lane == 63) ws[wave] = v;
    __syncthreads();
    int off = partial[blockIdx.x];
    for (int w = 0; w < 4; ++w) if (w < wave) off += ws[w];
    if (i < NN) cursor[i] = v - orig + off;
}

__global__ void k_scatter(const int* __restrict__ ei, int* __restrict__ cursor,
                          int* __restrict__ perm) {
    int e = blockIdx.x * blockDim.x + threadIdx.x;
    if (e < NE) {
        int s = ei[e];
        int d = ei[NE + e];
        int pos = atomicAdd(&cursor[d], 1);
        perm[pos] = s;
    }
}

// ---------------- packing ----------------

__global__ void k_pack_x(const float* __restrict__ x, unsigned* __restrict__ xp) {
    int i = blockIdx.x * blockDim.x + threadIdx.x;
    constexpr int TOT = NN * 128 / 4;
    if (i < TOT) {
        float4 v = ((const float4*)x)[i];
        uint4 o;
        o.x = pack_split(v.x); o.y = pack_split(v.y);
        o.z = pack_split(v.z); o.w = pack_split(v.w);
        ((uint4*)xp)[i] = o;
    }
}

// Wl,Wr [128 out][128 in] fp32 -> combined hi/lo bf16 planes [128 c][256 k]
__global__ void k_pack_w(const float* __restrict__ Wl, const float* __restrict__ Wr,
                         unsigned short* __restrict__ whi, unsigned short* __restrict__ wlo) {
    int i = blockIdx.x * blockDim.x + threadIdx.x;
    if (i < 128 * 256) {
        int c = i >> 8;
        int k = i & 255;
        float v = (k < 128) ? Wl[c * 128 + k] : Wr[c * 128 + (k - 128)];
        unsigned short hi = bf16_rne(v);
        whi[i] = hi;
        wlo[i] = bf16_rne(v - bf16_f(hi));
    }
}

__global__ void k_init_out(float* __restrict__ out, const float* __restrict__ bf) {
    int i = blockIdx.x * blockDim.x + threadIdx.x;
    if (i < NN) out[i] = bf[0];
}

// ---------------- aggregate (mean over CSR neighbors) ----------------
// one wave per node; lane l holds cols [2l, 2l+1] (packed uint2).
// 16-deep unroll -> 16 outstanding 512B row gathers (8KB in flight/wave).
__global__ __launch_bounds__(256) void k_aggregate(const unsigned* __restrict__ hp,
        const int* __restrict__ cursor, const int* __restrict__ cnt,
        const int* __restrict__ perm, unsigned* __restrict__ outp) {
    int wave = __builtin_amdgcn_readfirstlane(threadIdx.x >> 6);
    int lane = threadIdx.x & 63;
    int node = blockIdx.x * 4 + wave;
    if (node >= NN) return;
    int deg = cnt[node];
    int start = cursor[node] - deg;
    const uint2* base = (const uint2*)hp;    // row stride = 64 uint2
    float ax = 0.f, ay = 0.f;
    int j = 0;
    for (; j + 16 <= deg; j += 16) {
        int s[16];
#pragma unroll
        for (int u = 0; u < 16; ++u) s[u] = perm[start + j + u];
        uint2 q[16];
#pragma unroll
        for (int u = 0; u < 16; ++u) q[u] = base[(size_t)s[u] * 64 + lane];
#pragma unroll
        for (int u = 0; u < 16; ++u) { ax += unpack_f(q[u].x); ay += unpack_f(q[u].y); }
    }
    for (; j + 4 <= deg; j += 4) {
        int s[4];
#pragma unroll
        for (int u = 0; u < 4; ++u) s[u] = perm[start + j + u];
        uint2 q[4];
#pragma unroll
        for (int u = 0; u < 4; ++u) q[u] = base[(size_t)s[u] * 64 + lane];
#pragma unroll
        for (int u = 0; u < 4; ++u) { ax += unpack_f(q[u].x); ay += unpack_f(q[u].y); }
    }
    for (; j < deg; ++j) {
        int s = perm[start + j];
        uint2 q = base[(size_t)s * 64 + lane];
        ax += unpack_f(q.x);
        ay += unpack_f(q.y);
    }
    float inv = 1.0f / (float)(deg > 1 ? deg : 1);
    uint2 o;
    o.x = pack_split(ax * inv);
    o.y = pack_split(ay * inv);
    ((uint2*)(outp + (size_t)node * 128))[lane] = o;
}

// ---------------- weight-stationary MFMA GEMM (grid-stride) ----------------
// out[n][c] = relu( bias[c] + sum_k [A0|A1][n][k] W[c][k] )
// Wave w owns cols [32w,32w+32): B hi/lo frags hoisted to 128 VGPRs once,
// live across the tile loop. In-place safe: each tile owned by one block;
// __syncthreads() between the block's reads and writes of its rows.
__global__ __launch_bounds__(256, 2) void k_gemm_ws(
        const unsigned* __restrict__ A0p, const unsigned* __restrict__ A1p,
        const unsigned short* __restrict__ Whi, const unsigned short* __restrict__ Wlo,
        const float* __restrict__ bias, unsigned* __restrict__ outp) {
    int wave = __builtin_amdgcn_readfirstlane(threadIdx.x >> 6);
    int lane = threadIdx.x & 63;
    int row = lane & 15;        // A row in tile / D col in ct-tile
    int kb = lane >> 4;         // k-subblock 0..3
    int ct0 = wave * 2;

    bf16x8 bh[2][8], bl[2][8];
#pragma unroll
    for (int c = 0; c < 2; ++c)
#pragma unroll
        for (int kc = 0; kc < 8; ++kc) {
            size_t widx = (size_t)((ct0 + c) * 16 + row) * 256 + kc * 32 + kb * 8;
            bh[c][kc] = *(const bf16x8*)(Whi + widx);
            bl[c][kc] = *(const bf16x8*)(Wlo + widx);
        }
    float b0 = bias[ct0 * 16 + row];
    float b1 = bias[ct0 * 16 + 16 + row];

    for (int t = blockIdx.x; t < NTILE; t += gridDim.x) {
        int n0 = t * 16;
        const unsigned* a0 = A0p + (size_t)(n0 + row) * 128 + kb * 8;
        const unsigned* a1 = A1p + (size_t)(n0 + row) * 128 + kb * 8;
        f32x4 acc0 = {0.f, 0.f, 0.f, 0.f};
        f32x4 acc1 = {0.f, 0.f, 0.f, 0.f};
#pragma unroll
        for (int kc = 0; kc < 8; ++kc) {
            const unsigned* ap = ((kc < 4) ? a0 : a1) + (kc & 3) * 32;
            uint4 q0 = *(const uint4*)ap;
            uint4 q1 = *(const uint4*)(ap + 4);
            unsigned pk[8] = {q0.x, q0.y, q0.z, q0.w, q1.x, q1.y, q1.z, q1.w};
            bf16x8 ah, al;
#pragma unroll
            for (int j = 0; j < 8; ++j) {
                ah[j] = (short)(pk[j] >> 16);
                al[j] = (short)(pk[j] & 0xFFFFu);
            }
            acc0 = __builtin_amdgcn_mfma_f32_16x16x32_bf16(ah, bh[0][kc], acc0, 0, 0, 0);
            acc0 = __builtin_amdgcn_mfma_f32_16x16x32_bf16(al, bh[0][kc], acc0, 0, 0, 0);
            acc0 = __builtin_amdgcn_mfma_f32_16x16x32_bf16(ah, bl[0][kc], acc0, 0, 0, 0);
            acc1 = __builtin_amdgcn_mfma_f32_16x16x32_bf16(ah, bh[1][kc], acc1, 0, 0, 0);
            acc1 = __builtin_amdgcn_mfma_f32_16x16x32_bf16(al, bh[1][kc], acc1, 0, 0, 0);
            acc1 = __builtin_amdgcn_mfma_f32_16x16x32_bf16(ah, bl[1][kc], acc1, 0, 0, 0);
        }
        __syncthreads();   // all waves' reads of this tile's rows precede writes
        int cb0 = ct0 * 16 + row;
#pragma unroll
        for (int r = 0; r < 4; ++r) {
            int n = n0 + kb * 4 + r;         // D: col=lane&15, row=(lane>>4)*4+reg
            unsigned* orow = outp + (size_t)n * 128;
            orow[cb0]      = pack_split(fmaxf(acc0[r] + b0, 0.f));
            orow[cb0 + 16] = pack_split(fmaxf(acc1[r] + b1, 0.f));
        }
    }
}

// layer-2 variant: head fused — out[n] += sum_c relu(h3[n][c]) * Wf[c]
__global__ __launch_bounds__(256, 2) void k_gemm_head(
        const unsigned* __restrict__ A0p, const unsigned* __restrict__ A1p,
        const unsigned short* __restrict__ Whi, const unsigned short* __restrict__ Wlo,
        const float* __restrict__ bias, const float* __restrict__ Wf,
        float* __restrict__ out) {
    int wave = __builtin_amdgcn_readfirstlane(threadIdx.x >> 6);
    int lane = threadIdx.x & 63;
    int row = lane & 15;
    int kb = lane >> 4;
    int ct0 = wave * 2;

    bf16x8 bh[2][8], bl[2][8];
#pragma unroll
    for (int c = 0; c < 2; ++c)
#pragma unroll
        for (int kc = 0; kc < 8; ++kc) {
            size_t widx = (size_t)((ct0 + c) * 16 + row) * 256 + kc * 32 + kb * 8;
            bh[c][kc] = *(const bf16x8*)(Whi + widx);
            bl[c][kc] = *(const bf16x8*)(Wlo + widx);
        }
    float b0 = bias[ct0 * 16 + row];
    float b1 = bias[ct0 * 16 + 16 + row];
    float w0 = Wf[ct0 * 16 + row];
    float w1 = Wf[ct0 * 16 + 16 + row];

    for (int t = blockIdx.x; t < NTILE; t += gridDim.x) {
        int n0 = t * 16;
        const unsigned* a0 = A0p + (size_t)(n0 + row) * 128 + kb * 8;
        const unsigned* a1 = A1p + (size_t)(n0 + row) * 128 + kb * 8;
        f32x4 acc0 = {0.f, 0.f, 0.f, 0.f};
        f32x4 acc1 = {0.f, 0.f, 0.f, 0.f};
#pragma unroll
        for (int kc = 0; kc < 8; ++kc) {
            const unsigned* ap = ((kc < 4) ? a0 : a1) + (kc & 3) * 32;
            uint4 q0 = *(const uint4*)ap;
            uint4 q1 = *(const uint4*)(ap + 4);
            unsigned pk[8] = {q0.x, q0.y, q0.z, q0.w, q1.x, q1.y, q1.z, q1.w};
            bf16x8 ah, al;
#pragma unroll
            for (int j = 0; j < 8; ++j) {
                ah[j] = (short)(pk[j] >> 16);
                al[j] = (short)(pk[j] & 0xFFFFu);
            }
            acc0 = __builtin_amdgcn_mfma_f32_16x16x32_bf16(ah, bh[0][kc], acc0, 0, 0, 0);
            acc0 = __builtin_amdgcn_mfma_f32_16x16x32_bf16(al, bh[0][kc], acc0, 0, 0, 0);
            acc0 = __builtin_amdgcn_mfma_f32_16x16x32_bf16(ah, bl[0][kc], acc0, 0, 0, 0);
            acc1 = __builtin_amdgcn_mfma_f32_16x16x32_bf16(ah, bh[1][kc], acc1, 0, 0, 0);
            acc1 = __builtin_amdgcn_mfma_f32_16x16x32_bf16(al, bh[1][kc], acc1, 0, 0, 0);
            acc1 = __builtin_amdgcn_mfma_f32_16x16x32_bf16(ah, bl[1][kc], acc1, 0, 0, 0);
        }
        float part[4];
#pragma unroll
        for (int r = 0; r < 4; ++r)
            part[r] = fmaxf(acc0[r] + b0, 0.f) * w0 + fmaxf(acc1[r] + b1, 0.f) * w1;
#pragma unroll
        for (int o = 1; o < 16; o <<= 1) {
#pragma unroll
            for (int r = 0; r < 4; ++r) part[r] += __shfl_xor(part[r], o);
        }
        if (row == 0) {
#pragma unroll
            for (int r = 0; r < 4; ++r) atomicAdd(&out[n0 + kb * 4 + r], part[r]);
        }
    }
}

extern "C" void kernel_launch(void* const* d_in, const int* in_sizes, int n_in,
                              void* d_out, int out_size, void* d_ws, size_t ws_size,
                              hipStream_t stream) {
    const float* x   = (const float*)d_in[0];
    const int*   ei  = (const int*)d_in[1];
    const float* Wl0 = (const float*)d_in[2];
    const float* bl0 = (const float*)d_in[3];
    const float* Wr0 = (const float*)d_in[4];
    const float* Wl1 = (const float*)d_in[5];
    const float* bl1 = (const float*)d_in[6];
    const float* Wr1 = (const float*)d_in[7];
    const float* Wl2 = (const float*)d_in[8];
    const float* bl2 = (const float*)d_in[9];
    const float* Wr2 = (const float*)d_in[10];
    const float* Wf  = (const float*)d_in[11];
    const float* bf  = (const float*)d_in[12];
    float* out = (float*)d_out;

    char* p = (char*)d_ws;
    auto alloc = [&](size_t n) { void* r = (void*)p; p += (n + 255) & ~(size_t)255; return r; };
    int*            cnt     = (int*)alloc((size_t)NN * 4);
    int*            cursor  = (int*)alloc((size_t)NN * 4);
    int*            partial = (int*)alloc(256 * 4);
    int*            perm    = (int*)alloc((size_t)NE * 4);
    unsigned*       sbuf    = (unsigned*)alloc((size_t)NN * 128 * 4);
    unsigned*       hp      = (unsigned*)alloc((size_t)NN * 128 * 4);
    unsigned short* whi     = (unsigned short*)alloc((size_t)3 * 128 * 256 * 2);
    unsigned short* wlo     = (unsigned short*)alloc((size_t)3 * 128 * 256 * 2);

    dim3 b256(256);
    // CSR build
    k_zero_int<<<dim3((NN + 255) / 256), b256, 0, stream>>>(cnt, NN);
    k_count<<<dim3((NE + 255) / 256), b256, 0, stream>>>(ei, cnt);
    k_chunk_sums<<<dim3(NCH), b256, 0, stream>>>(cnt, partial);
    k_scan_partials<<<dim3(1), b256, 0, stream>>>(partial, NCH);
    k_scan_chunks<<<dim3(NCH), b256, 0, stream>>>(cnt, partial, cursor);
    k_scatter<<<dim3((NE + 255) / 256), b256, 0, stream>>>(ei, cursor, perm);

    // packing + out init
    k_pack_x<<<dim3((NN * 128 / 4 + 255) / 256), b256, 0, stream>>>(x, hp);
    k_pack_w<<<dim3(128), b256, 0, stream>>>(Wl0, Wr0, whi + 0 * 32768, wlo + 0 * 32768);
    k_pack_w<<<dim3(128), b256, 0, stream>>>(Wl1, Wr1, whi + 1 * 32768, wlo + 1 * 32768);
    k_pack_w<<<dim3(128), b256, 0, stream>>>(Wl2, Wr2, whi + 2 * 32768, wlo + 2 * 32768);
    k_init_out<<<dim3((NN + 255) / 256), b256, 0, stream>>>(out, bf);

    dim3 gAgg((NN + 3) / 4);    // 1 node/wave, 4 per block
    dim3 gGemm(512);            // 2 blocks/CU; grid-stride over 3125 tiles

    // layer 0
    k_aggregate<<<gAgg, b256, 0, stream>>>(hp, cursor, cnt, perm, sbuf);
    k_gemm_ws<<<gGemm, b256, 0, stream>>>(sbuf, hp, whi + 0 * 32768, wlo + 0 * 32768, bl0, hp);
    // layer 1 (in place)
    k_aggregate<<<gAgg, b256, 0, stream>>>(hp, cursor, cnt, perm, sbuf);
    k_gemm_ws<<<gGemm, b256, 0, stream>>>(sbuf, hp, whi + 1 * 32768, wlo + 1 * 32768, bl1, hp);
    // layer 2 + fused head
    k_aggregate<<<gAgg, b256, 0, stream>>>(hp, cursor, cnt, perm, sbuf);
    k_gemm_head<<<gGemm, b256, 0, stream>>>(sbuf, hp, whi + 2 * 32768, wlo + 2 * 32768, bl2, Wf, out);
}